// Round 6
// baseline (471.374 us; speedup 1.0000x reference)
//
#include <hip/hip_runtime.h>
#include <hip/hip_bf16.h>
#include <math.h>

typedef __bf16 bf16;
typedef __attribute__((ext_vector_type(8))) __bf16 bf16x8;
typedef __attribute__((ext_vector_type(4))) __bf16 bf16x4;
typedef __attribute__((ext_vector_type(4))) float f32x4;

constexpr int BM = 128, BN = 128, BK = 32;

enum { EPI_PLAIN = 0, EPI_GELU = 1, EPI_RES = 2, EPI_GATE = 3 };

__device__ __forceinline__ void async16(const void* g, void* l) {
  __builtin_amdgcn_global_load_lds(
      (const __attribute__((address_space(1))) void*)g,
      (__attribute__((address_space(3))) void*)l, 16, 0, 0);
}

// barrier draining LDS ops but NOT the global_load_lds queue (vmcnt counted).
__device__ __forceinline__ void bar_lgkm() {
  asm volatile("s_waitcnt lgkmcnt(0)\n\ts_barrier" ::: "memory");
}

#define WAIT_VM(n) asm volatile("s_waitcnt vmcnt(" #n ")" ::: "memory")

// ---------------------------------------------------------------------------
// bf16 GEMM, C = A[M,K] @ B[N,K]^T + epilogue.  128x128 tile, 8 waves
// (2x4 grid of 64x32 wave tiles) -- round-4 structure (G2 71us, occ 64%,
// conflicts 0), with round-6 change:
//   B SKIPS LDS. Weights are L2-resident per XCD (XCD-chunked remap);
//   per-wave B reuse is only 2x, so each wave loads its own B fragments
//   directly global->register (16B-aligned dwordx4, one 64B line per 4
//   lanes), register ping-pong bE/bO with 1-step prefetch (unroll-by-2,
//   static names per scratch rule). Effects: LDS reads/block-step 48->32,
//   DMA writes -1/3 (LDS pipe was 65% of cycles in round-4 accounting);
//   LDS 32->16 KB -> up to 4 resident blocks (32-wave cap).
// A side unchanged and HW-verified: LDS dbuf [128][32] + XOR chunk swizzle
// (conflicts == 0), counted vmcnt. Steady outstanding before the wait:
// {A(t):1, B(t):2, A(t+1):1, B(t+1):2} -> WAIT_VM(3) retires tile t only.
// ---------------------------------------------------------------------------
template <typename CT, int EPI>
__global__ __launch_bounds__(512, 4) void gemm_bt_a(
    const bf16* __restrict__ A, const bf16* __restrict__ B, CT* __restrict__ C,
    const float* __restrict__ bias, const bf16* __restrict__ resid,
    const float* __restrict__ sup, const float* __restrict__ wsg,
    const float* __restrict__ bsg, int M, int N, int K) {
  __shared__ bf16 As[2][BM * BK];  // 8 KB per buf, 16 KB total

  const int tid = threadIdx.x;
  // XCD-chunked remap (bijective; nwg % 8 == 0 for all grids used here).
  const int nwg = gridDim.x;
  const int cpx = nwg >> 3;
  const int wg = blockIdx.x;
  const int sw = (wg & 7) * cpx + (wg >> 3);
  const int ntn = N >> 7;  // N / BN
  const int bm = sw / ntn, bn = sw - bm * ntn;

  const int lane = tid & 63;
  const int wv = tid >> 6;
  const int wm = (wv >> 2) * 64, wn = (wv & 3) * 32;  // 2x4 wave grid
  const int quad = lane >> 4, l16 = lane & 15;

  f32x4 acc[4][2];
#pragma unroll
  for (int i = 0; i < 4; i++)
#pragma unroll
    for (int j = 0; j < 2; j++) acc[i][j] = f32x4{0.f, 0.f, 0.f, 0.f};

  // ---- A staging (1 chunk/thread; linear LDS dest, source pre-swizzled) ----
  const int srow = tid >> 2;
  const int sq8 = ((tid & 3) ^ ((srow >> 1) & 3)) * 8;
  const bf16* pa = A + (size_t)(bm * BM + srow) * K + sq8;
  bf16* dA = &As[0][0] + wv * 512;  // wave-uniform base; HW adds lane*16B

  auto stgA = [&](int buf) {
    async16(pa, dA + buf * 4096);
    pa += BK;
  };

  // ---- A read side (HW-verified swizzled slot) ----
  const int slot8 = (quad ^ ((l16 >> 1) & 3)) * 8;

  // ---- B direct-load pointers: col j*16 blocks of this wave's wn ----
  const bf16* pb0 = B + (size_t)(bn * BN + wn + l16) * K + quad * 8;
  const bf16* pb1 = pb0 + (size_t)16 * K;

  bf16x8 bE0, bE1, bO0, bO1;

  // prologue: tile 0 (A DMA + B regs) in flight (3 loads/thread)
  stgA(0);
  bE0 = *(const bf16x8*)(pb0);
  bE1 = *(const bf16x8*)(pb1);

  auto compute = [&](int cur, bf16x8 b0, bf16x8 b1) {
    bf16x8 af[4];
#pragma unroll
    for (int i = 0; i < 4; i++)
      af[i] = *(const bf16x8*)&As[cur][(wm + i * 16 + l16) * BK + slot8];
#pragma unroll
    for (int i = 0; i < 4; i++) {
      acc[i][0] = __builtin_amdgcn_mfma_f32_16x16x32_bf16(af[i], b0, acc[i][0], 0, 0, 0);
      acc[i][1] = __builtin_amdgcn_mfma_f32_16x16x32_bf16(af[i], b1, acc[i][1], 0, 0, 0);
    }
  };

  const int nt = K / BK;  // even (24 or 48)
  for (int t = 0; t < nt; t += 2) {
    // ---- even step: compute buf0/bE, prefetch t+1 -> buf1/bO ----
    stgA(1);
    {
      const size_t ko = (size_t)(t + 1) * BK;
      bO0 = *(const bf16x8*)(pb0 + ko);
      bO1 = *(const bf16x8*)(pb1 + ko);
    }
    WAIT_VM(3);  // tile t landed (A DMA + bE); tile t+1's 3 stay in flight
    bar_lgkm();
    compute(0, bE0, bE1);
    bar_lgkm();

    // ---- odd step: compute buf1/bO, prefetch t+2 -> buf0/bE ----
    if (t + 2 < nt) {
      stgA(0);
      const size_t ko = (size_t)(t + 2) * BK;
      bE0 = *(const bf16x8*)(pb0 + ko);
      bE1 = *(const bf16x8*)(pb1 + ko);
      WAIT_VM(3);
    } else {
      WAIT_VM(0);  // tail: drain last tile
    }
    bar_lgkm();
    compute(1, bO0, bO1);
    bar_lgkm();
  }

  // ---- epilogue ----
#pragma unroll
  for (int i = 0; i < 4; i++) {
    int row0 = bm * BM + wm + i * 16 + quad * 4;
#pragma unroll
    for (int j = 0; j < 2; j++) {
      int col = bn * BN + wn + j * 16 + l16;
#pragma unroll
      for (int r = 0; r < 4; r++) {
        int row = row0 + r;
        size_t idx = (size_t)row * N + col;
        float v = acc[i][j][r];
        if constexpr (EPI == EPI_PLAIN) {
          C[idx] = (CT)v;
        } else if constexpr (EPI == EPI_GELU) {
          v += bias[col];
          float gl = 0.5f * v * (1.0f + erff(v * 0.70710678118654752f));
          C[idx] = (CT)gl;
        } else if constexpr (EPI == EPI_RES) {
          v += bias[col] + (float)resid[idx];
          C[idx] = (CT)v;
        } else {  // EPI_GATE
          v += bias[col];
          float g1 = 1.0f / (1.0f + expf(-v));
          float z = sup[row] * wsg[col] + bsg[col];
          float g2 = 1.0f / (1.0f + expf(-z));
          C[idx] = (CT)(g1 * g2);
        }
      }
    }
  }
}

// ---------------- chunked parallel scan ----------------
constexpr int SC_CH = 32, SC_NCH = 16, SC_CW = 32;

__global__ __launch_bounds__(512) void scan2_kernel(const float* __restrict__ g,
                                                    const bf16* __restrict__ xt,
                                                    bf16* __restrict__ s, int T, int C) {
  __shared__ float lA[SC_NCH][SC_CW];
  __shared__ float lB[SC_NCH][SC_CW];
  __shared__ float lC[SC_NCH][SC_CW];
  const int cl = threadIdx.x & (SC_CW - 1);
  const int ch = threadIdx.x / SC_CW;
  const int c = blockIdx.x * SC_CW + cl;
  const int n = blockIdx.y;
  const size_t base = ((size_t)n * T + ch * SC_CH) * C + c;

  float a_arr[SC_CH], sl[SC_CH];
  float A = 1.f, B = 0.f;
#pragma unroll
  for (int t = 0; t < SC_CH; ++t) {
    size_t idx = base + (size_t)t * C;
    float gv = g[idx], xv = (float)xt[idx];
    float at = 1.0f - gv;
    a_arr[t] = at;
    B = at * B + gv * xv;
    sl[t] = B;
    A *= at;
  }
  lA[ch][cl] = A;
  lB[ch][cl] = B;
  __syncthreads();
  if (ch == 0) {
    float carry = 0.f;
#pragma unroll
    for (int j = 0; j < SC_NCH; ++j) {
      lC[j][cl] = carry;
      carry = lA[j][cl] * carry + lB[j][cl];
    }
  }
  __syncthreads();
  const float carry = lC[ch][cl];
  float P = 1.f;
#pragma unroll
  for (int t = 0; t < SC_CH; ++t) {
    P *= a_arr[t];
    s[base + (size_t)t * C] = (bf16)(sl[t] + P * carry);
  }
}

// ---------------- weight converts (fused 5-way, scalar) ----------------
__global__ __launch_bounds__(256) void cvt5_kernel(
    const float* s0, bf16* d0, int n0, const float* s1, bf16* d1, int n1,
    const float* s2, bf16* d2, int n2, const float* s3, bf16* d3, int n3,
    const float* s4, bf16* d4, int n4) {
  const float* s; bf16* d; int n;
  switch (blockIdx.y) {
    case 0: s = s0; d = d0; n = n0; break;
    case 1: s = s1; d = d1; n = n1; break;
    case 2: s = s2; d = d2; n = n2; break;
    case 3: s = s3; d = d3; n = n3; break;
    default: s = s4; d = d4; n = n4; break;
  }
  int i = blockIdx.x * 256 + threadIdx.x;
  if (i < n) d[i] = (bf16)s[i];
}

// ---------------- vectorized fp32 -> bf16 (x_seq), n % 4 == 0 ----------------
__global__ __launch_bounds__(256) void cvtx_kernel(const float* __restrict__ in,
                                                   bf16* __restrict__ out, int n4) {
  int i = blockIdx.x * 256 + threadIdx.x;
  if (i < n4) {
    f32x4 v = *(const f32x4*)(in + (size_t)i * 4);
    bf16x4 b;
    b[0] = (bf16)v[0]; b[1] = (bf16)v[1]; b[2] = (bf16)v[2]; b[3] = (bf16)v[3];
    *(bf16x4*)(out + (size_t)i * 4) = b;
  }
}

extern "C" void kernel_launch(void* const* d_in, const int* in_sizes, int n_in,
                              void* d_out, int out_size, void* d_ws, size_t ws_size,
                              hipStream_t stream) {
  const float* x_seq = (const float*)d_in[0];
  const float* sup = (const float*)d_in[1];
  const float* W_in = (const float*)d_in[2];
  const float* W_out = (const float*)d_in[3];
  const float* W_bg = (const float*)d_in[4];
  const float* b_bg = (const float*)d_in[5];
  const float* W_sg = (const float*)d_in[6];
  const float* b_sg = (const float*)d_in[7];
  const float* W_f1 = (const float*)d_in[8];
  const float* b_f1 = (const float*)d_in[9];
  const float* W_f2 = (const float*)d_in[10];
  const float* b_f2 = (const float*)d_in[11];

  const int Nb = 32, T = 512, C = 768, H = 1536;
  const int M = Nb * T;  // 16384

  char* ws = (char*)d_ws;
  size_t off = 0;
  auto alloc = [&](size_t bytes) {
    void* p = ws + off;
    off += (bytes + 255) & ~(size_t)255;
    return p;
  };
  bf16* Win_bf = (bf16*)alloc((size_t)C * C * 2);
  bf16* Wf1_bf = (bf16*)alloc((size_t)H * C * 2);
  bf16* Wf2_bf = (bf16*)alloc((size_t)C * H * 2);
  bf16* Wbg_bf = (bf16*)alloc((size_t)C * C * 2);
  bf16* Wout_bf = (bf16*)alloc((size_t)C * C * 2);
  bf16* xs_bf = (bf16*)alloc((size_t)M * C * 2);  // x_seq bf16
  bf16* x_bf = (bf16*)alloc((size_t)M * C * 2);   // x; reused as s after G3
  bf16* h_bf = (bf16*)alloc((size_t)M * H * 2);
  bf16* xt_bf = (bf16*)alloc((size_t)M * C * 2);
  float* g_f = (float*)alloc((size_t)M * C * 4);
  bf16* s_bf = x_bf;  // x dead after G3

  cvt5_kernel<<<dim3((H * C + 255) / 256, 5), 256, 0, stream>>>(
      W_in, Win_bf, C * C, W_f1, Wf1_bf, H * C, W_f2, Wf2_bf, C * H,
      W_bg, Wbg_bf, C * C, W_out, Wout_bf, C * C);
  cvtx_kernel<<<(M * C / 4 + 255) / 256, 256, 0, stream>>>(x_seq, xs_bf, M * C / 4);

  dim3 blk(512);
  // 1D grids (XCD remap in-kernel); nwg % 8 == 0 for all of these.
  // G1: x = x_seq @ W_in^T
  gemm_bt_a<bf16, EPI_PLAIN><<<dim3((M / BM) * (C / BN)), blk, 0, stream>>>(
      xs_bf, Win_bf, x_bf, nullptr, nullptr, nullptr, nullptr, nullptr, M, C, C);
  // G2: h = gelu(x @ W_f1^T + b_f1)
  gemm_bt_a<bf16, EPI_GELU><<<dim3((M / BM) * (H / BN)), blk, 0, stream>>>(
      x_bf, Wf1_bf, h_bf, b_f1, nullptr, nullptr, nullptr, nullptr, M, H, C);
  // G3: xt = x + h @ W_f2^T + b_f2
  gemm_bt_a<bf16, EPI_RES><<<dim3((M / BM) * (C / BN)), blk, 0, stream>>>(
      h_bf, Wf2_bf, xt_bf, b_f2, x_bf, nullptr, nullptr, nullptr, M, C, H);
  // G4: g = sigmoid(xt @ W_bg^T + b_bg) * sigmoid(sup*W_sg + b_sg)  (fp32 out)
  gemm_bt_a<float, EPI_GATE><<<dim3((M / BM) * (C / BN)), blk, 0, stream>>>(
      xt_bf, Wbg_bf, g_f, b_bg, nullptr, sup, W_sg, b_sg, M, C, C);
  // scan
  scan2_kernel<<<dim3(C / SC_CW, Nb), dim3(SC_CW * SC_NCH), 0, stream>>>(
      g_f, xt_bf, s_bf, T, C);
  // G6: out = s @ W_out^T (fp32 out)
  gemm_bt_a<float, EPI_PLAIN><<<dim3((M / BM) * (C / BN)), blk, 0, stream>>>(
      s_bf, Wout_bf, (float*)d_out, nullptr, nullptr, nullptr, nullptr, nullptr, M, C, C);
}

// Round 7
// 381.363 us; speedup vs baseline: 1.2360x; 1.2360x over previous
//
#include <hip/hip_runtime.h>
#include <hip/hip_bf16.h>
#include <math.h>

typedef __bf16 bf16;
typedef __attribute__((ext_vector_type(8))) __bf16 bf16x8;
typedef __attribute__((ext_vector_type(4))) __bf16 bf16x4;
typedef __attribute__((ext_vector_type(4))) float f32x4;

constexpr int BM = 128, BN = 128, BK = 32;

enum { EPI_PLAIN = 0, EPI_GELU = 1, EPI_RES = 2, EPI_GATE = 3 };

__device__ __forceinline__ void async16(const void* g, void* l) {
  __builtin_amdgcn_global_load_lds(
      (const __attribute__((address_space(1))) void*)g,
      (__attribute__((address_space(3))) void*)l, 16, 0, 0);
}

// barrier draining LDS ops but NOT the global_load_lds queue (vmcnt counted).
__device__ __forceinline__ void bar_lgkm() {
  asm volatile("s_waitcnt lgkmcnt(0)\n\ts_barrier" ::: "memory");
}

#define WAIT_VM(n) asm volatile("s_waitcnt vmcnt(" #n ")" ::: "memory")

// ---------------------------------------------------------------------------
// bf16 GEMM, C = A[M,K] @ B[N,K]^T + epilogue.  128x128 tile.
// Round-7: occupancy attack. Evidence: realized blocks/CU ~= 2.5 in EVERY
// config tried (R0/R2 256thr: 10 waves; R4 512thr: 20.5 waves -> G2 79->71);
// the dispatcher wall is in BLOCKS, so waves/CU scales with block size.
//   - 1024 threads = 16 waves, 4x4 grid of 32x32 wave tiles (acc 16 f32,
//     ~50 total regs -> two 16-wave blocks fit the 2048-reg/CU budget ->
//     32-wave cap reachable).
//   - staging: 1024 chunks = 1 async16/thread/step (waves 0-7 A, 8-15 B),
//     dbuf 32 KB, counted WAIT_VM(1) (never 0 mid-loop).
//   - ds_read pattern and XOR chunk swizzle BYTE-IDENTICAL in form to the
//     HW-verified R4 one (row offsets multiples of 32; parity class depends
//     only on l16) -- no new bank derivation (R5 lesson).
//   - XCD-chunked remap kept (FETCH 34->31.8 MB in R4).
// AFP32=1 (G1 only): A staged from fp32 x_seq -- threads 0-511 load 2xf32x4
// from the pre-swizzled source, convert, ds_write_b128 to the linear chunk
// the DMA would have written. Kills the separate cvtx pass (~16 us).
// Per-wave vmcnt ledgers stay uniform: A-reg waves WAIT_VM(2), DMA waves
// WAIT_VM(1) (wave-uniform branch).
// ---------------------------------------------------------------------------
template <typename CT, int EPI, int AFP32>
__global__ __launch_bounds__(1024, 2) void gemm_bt_a(
    const bf16* __restrict__ A, const float* __restrict__ Af,
    const bf16* __restrict__ B, CT* __restrict__ C,
    const float* __restrict__ bias, const bf16* __restrict__ resid,
    const float* __restrict__ sup, const float* __restrict__ wsg,
    const float* __restrict__ bsg, int M, int N, int K) {
  __shared__ bf16 As[2][BM * BK];  // 8 KB per buf
  __shared__ bf16 Bs[2][BN * BK];

  const int tid = threadIdx.x;
  // XCD-chunked remap (bijective; nwg % 8 == 0 for all grids used here).
  const int nwg = gridDim.x;
  const int cpx = nwg >> 3;
  const int wg = blockIdx.x;
  const int sw = (wg & 7) * cpx + (wg >> 3);
  const int ntn = N >> 7;  // N / BN
  const int bm = sw / ntn, bn = sw - bm * ntn;

  const int lane = tid & 63;
  const int wv = tid >> 6;
  const int wm = (wv >> 2) * 32, wn = (wv & 3) * 32;  // 4x4 wave grid
  const int quad = lane >> 4, l16 = lane & 15;
  const int slot8 = (quad ^ ((l16 >> 1) & 3)) * 8;  // HW-verified read swizzle

  f32x4 acc[2][2];
#pragma unroll
  for (int i = 0; i < 2; i++)
#pragma unroll
    for (int j = 0; j < 2; j++) acc[i][j] = f32x4{0.f, 0.f, 0.f, 0.f};

  // ---- staging assignment: waves 0-7 -> A chunk tid, waves 8-15 -> B ----
  const bool isA = (wv < 8);
  const int cid = tid & 511;  // chunk id within the 8 KB tile
  const int srow = cid >> 2;
  const int sq8 = ((cid & 3) ^ ((srow >> 1) & 3)) * 8;  // pre-swizzled source

  const bf16* pg = nullptr;   // DMA source base (A when !AFP32, or B)
  const float* pf = nullptr;  // fp32 A source base (AFP32 G1 path)
  if (isA) {
    if constexpr (AFP32)
      pf = Af + (size_t)(bm * BM + srow) * K + sq8;
    else
      pg = A + (size_t)(bm * BM + srow) * K + sq8;
  } else {
    pg = B + (size_t)(bn * BN + srow) * K + sq8;
  }
  bf16* dst = (isA ? &As[0][0] : &Bs[0][0]) + (wv & 7) * 512;  // wave-uniform
  bf16* wrA = &As[0][0] + cid * 8;  // per-thread ds_write dest (AFP32 path)

  const int nt = K / BK;  // 24 or 48 (even)

  // ---- prologue: tile 0 in flight ----
  f32x4 fE0, fE1, fO0, fO1;
  if constexpr (AFP32) {
    if (isA) {
      fE0 = *(const f32x4*)pf;
      fE1 = *(const f32x4*)(pf + 4);
    } else {
      async16(pg, dst);
    }
  } else {
    async16(pg, dst);
  }

  auto step = [&](int buf, f32x4& c0, f32x4& c1, f32x4& n0, f32x4& n1, int t) {
    const bool more = (t + 1) < nt;
    // ---- stage next tile, counted wait for current ----
    if constexpr (AFP32) {
      if (isA) {
        if (more) {
          const float* p = pf + (size_t)(t + 1) * BK;
          n0 = *(const f32x4*)p;
          n1 = *(const f32x4*)(p + 4);
          WAIT_VM(2);  // tile t's 2 loads done; t+1's 2 stay in flight
        } else {
          WAIT_VM(0);
        }
        bf16x8 v;
        v[0] = (bf16)c0[0]; v[1] = (bf16)c0[1]; v[2] = (bf16)c0[2]; v[3] = (bf16)c0[3];
        v[4] = (bf16)c1[0]; v[5] = (bf16)c1[1]; v[6] = (bf16)c1[2]; v[7] = (bf16)c1[3];
        *(bf16x8*)(wrA + buf * 4096) = v;  // ds_write_b128, linear chunk
      } else {
        if (more) {
          async16(pg + (size_t)(t + 1) * BK, dst + (buf ^ 1) * 4096);
          WAIT_VM(1);
        } else {
          WAIT_VM(0);
        }
      }
    } else {
      if (more) {
        async16(pg + (size_t)(t + 1) * BK, dst + (buf ^ 1) * 4096);
        WAIT_VM(1);  // tile t's DMA done; t+1's stays in flight
      } else {
        WAIT_VM(0);
      }
    }
    bar_lgkm();  // ds_writes drained + all staging of tile t visible

    // ---- compute tile t ----
    bf16x8 af0 = *(const bf16x8*)&As[buf][(wm + l16) * BK + slot8];
    bf16x8 af1 = *(const bf16x8*)&As[buf][(wm + 16 + l16) * BK + slot8];
    bf16x8 bf0 = *(const bf16x8*)&Bs[buf][(wn + l16) * BK + slot8];
    bf16x8 bf1 = *(const bf16x8*)&Bs[buf][(wn + 16 + l16) * BK + slot8];
    acc[0][0] = __builtin_amdgcn_mfma_f32_16x16x32_bf16(af0, bf0, acc[0][0], 0, 0, 0);
    acc[0][1] = __builtin_amdgcn_mfma_f32_16x16x32_bf16(af0, bf1, acc[0][1], 0, 0, 0);
    acc[1][0] = __builtin_amdgcn_mfma_f32_16x16x32_bf16(af1, bf0, acc[1][0], 0, 0, 0);
    acc[1][1] = __builtin_amdgcn_mfma_f32_16x16x32_bf16(af1, bf1, acc[1][1], 0, 0, 0);
    bar_lgkm();  // all waves done reading buf before next stage overwrites
  };

  for (int t = 0; t < nt; t += 2) {
    step(0, fE0, fE1, fO0, fO1, t);
    step(1, fO0, fO1, fE0, fE1, t + 1);
  }

  // ---- epilogue: 16 outputs/thread ----
#pragma unroll
  for (int i = 0; i < 2; i++) {
    int row0 = bm * BM + wm + i * 16 + quad * 4;
#pragma unroll
    for (int j = 0; j < 2; j++) {
      int col = bn * BN + wn + j * 16 + l16;
#pragma unroll
      for (int r = 0; r < 4; r++) {
        int row = row0 + r;
        size_t idx = (size_t)row * N + col;
        float v = acc[i][j][r];
        if constexpr (EPI == EPI_PLAIN) {
          C[idx] = (CT)v;
        } else if constexpr (EPI == EPI_GELU) {
          v += bias[col];
          float gl = 0.5f * v * (1.0f + erff(v * 0.70710678118654752f));
          C[idx] = (CT)gl;
        } else if constexpr (EPI == EPI_RES) {
          v += bias[col] + (float)resid[idx];
          C[idx] = (CT)v;
        } else {  // EPI_GATE
          v += bias[col];
          float g1 = 1.0f / (1.0f + expf(-v));
          float z = sup[row] * wsg[col] + bsg[col];
          float g2 = 1.0f / (1.0f + expf(-z));
          C[idx] = (CT)(g1 * g2);
        }
      }
    }
  }
}

// ---------------- chunked parallel scan ----------------
constexpr int SC_CH = 32, SC_NCH = 16, SC_CW = 32;

__global__ __launch_bounds__(512) void scan2_kernel(const float* __restrict__ g,
                                                    const bf16* __restrict__ xt,
                                                    bf16* __restrict__ s, int T, int C) {
  __shared__ float lA[SC_NCH][SC_CW];
  __shared__ float lB[SC_NCH][SC_CW];
  __shared__ float lC[SC_NCH][SC_CW];
  const int cl = threadIdx.x & (SC_CW - 1);
  const int ch = threadIdx.x / SC_CW;
  const int c = blockIdx.x * SC_CW + cl;
  const int n = blockIdx.y;
  const size_t base = ((size_t)n * T + ch * SC_CH) * C + c;

  float a_arr[SC_CH], sl[SC_CH];
  float A = 1.f, B = 0.f;
#pragma unroll
  for (int t = 0; t < SC_CH; ++t) {
    size_t idx = base + (size_t)t * C;
    float gv = g[idx], xv = (float)xt[idx];
    float at = 1.0f - gv;
    a_arr[t] = at;
    B = at * B + gv * xv;
    sl[t] = B;
    A *= at;
  }
  lA[ch][cl] = A;
  lB[ch][cl] = B;
  __syncthreads();
  if (ch == 0) {
    float carry = 0.f;
#pragma unroll
    for (int j = 0; j < SC_NCH; ++j) {
      lC[j][cl] = carry;
      carry = lA[j][cl] * carry + lB[j][cl];
    }
  }
  __syncthreads();
  const float carry = lC[ch][cl];
  float P = 1.f;
#pragma unroll
  for (int t = 0; t < SC_CH; ++t) {
    P *= a_arr[t];
    s[base + (size_t)t * C] = (bf16)(sl[t] + P * carry);
  }
}

// ---------------- weight converts (fused 5-way, scalar) ----------------
__global__ __launch_bounds__(256) void cvt5_kernel(
    const float* s0, bf16* d0, int n0, const float* s1, bf16* d1, int n1,
    const float* s2, bf16* d2, int n2, const float* s3, bf16* d3, int n3,
    const float* s4, bf16* d4, int n4) {
  const float* s; bf16* d; int n;
  switch (blockIdx.y) {
    case 0: s = s0; d = d0; n = n0; break;
    case 1: s = s1; d = d1; n = n1; break;
    case 2: s = s2; d = d2; n = n2; break;
    case 3: s = s3; d = d3; n = n3; break;
    default: s = s4; d = d4; n = n4; break;
  }
  int i = blockIdx.x * 256 + threadIdx.x;
  if (i < n) d[i] = (bf16)s[i];
}

extern "C" void kernel_launch(void* const* d_in, const int* in_sizes, int n_in,
                              void* d_out, int out_size, void* d_ws, size_t ws_size,
                              hipStream_t stream) {
  const float* x_seq = (const float*)d_in[0];
  const float* sup = (const float*)d_in[1];
  const float* W_in = (const float*)d_in[2];
  const float* W_out = (const float*)d_in[3];
  const float* W_bg = (const float*)d_in[4];
  const float* b_bg = (const float*)d_in[5];
  const float* W_sg = (const float*)d_in[6];
  const float* b_sg = (const float*)d_in[7];
  const float* W_f1 = (const float*)d_in[8];
  const float* b_f1 = (const float*)d_in[9];
  const float* W_f2 = (const float*)d_in[10];
  const float* b_f2 = (const float*)d_in[11];

  const int Nb = 32, T = 512, C = 768, H = 1536;
  const int M = Nb * T;  // 16384

  char* ws = (char*)d_ws;
  size_t off = 0;
  auto alloc = [&](size_t bytes) {
    void* p = ws + off;
    off += (bytes + 255) & ~(size_t)255;
    return p;
  };
  bf16* Win_bf = (bf16*)alloc((size_t)C * C * 2);
  bf16* Wf1_bf = (bf16*)alloc((size_t)H * C * 2);
  bf16* Wf2_bf = (bf16*)alloc((size_t)C * H * 2);
  bf16* Wbg_bf = (bf16*)alloc((size_t)C * C * 2);
  bf16* Wout_bf = (bf16*)alloc((size_t)C * C * 2);
  bf16* x_bf = (bf16*)alloc((size_t)M * C * 2);  // x; reused as s after G3
  bf16* h_bf = (bf16*)alloc((size_t)M * H * 2);
  bf16* xt_bf = (bf16*)alloc((size_t)M * C * 2);
  float* g_f = (float*)alloc((size_t)M * C * 4);
  bf16* s_bf = x_bf;  // x dead after G3

  cvt5_kernel<<<dim3((H * C + 255) / 256, 5), 256, 0, stream>>>(
      W_in, Win_bf, C * C, W_f1, Wf1_bf, H * C, W_f2, Wf2_bf, C * H,
      W_bg, Wbg_bf, C * C, W_out, Wout_bf, C * C);

  dim3 blk(1024);
  // 1D grids (XCD remap in-kernel); nwg % 8 == 0 for all of these.
  // G1: x = x_seq @ W_in^T  (A staged from fp32 in-kernel; no cvtx pass)
  gemm_bt_a<bf16, EPI_PLAIN, 1><<<dim3((M / BM) * (C / BN)), blk, 0, stream>>>(
      nullptr, x_seq, Win_bf, x_bf, nullptr, nullptr, nullptr, nullptr, nullptr, M, C, C);
  // G2: h = gelu(x @ W_f1^T + b_f1)
  gemm_bt_a<bf16, EPI_GELU, 0><<<dim3((M / BM) * (H / BN)), blk, 0, stream>>>(
      x_bf, nullptr, Wf1_bf, h_bf, b_f1, nullptr, nullptr, nullptr, nullptr, M, H, C);
  // G3: xt = x + h @ W_f2^T + b_f2
  gemm_bt_a<bf16, EPI_RES, 0><<<dim3((M / BM) * (C / BN)), blk, 0, stream>>>(
      h_bf, nullptr, Wf2_bf, xt_bf, b_f2, x_bf, nullptr, nullptr, nullptr, M, C, H);
  // G4: g = sigmoid(xt @ W_bg^T + b_bg) * sigmoid(sup*W_sg + b_sg)  (fp32 out)
  gemm_bt_a<float, EPI_GATE, 0><<<dim3((M / BM) * (C / BN)), blk, 0, stream>>>(
      xt_bf, nullptr, Wbg_bf, g_f, b_bg, nullptr, sup, W_sg, b_sg, M, C, C);
  // scan
  scan2_kernel<<<dim3(C / SC_CW, Nb), dim3(SC_CW * SC_NCH), 0, stream>>>(
      g_f, xt_bf, s_bf, T, C);
  // G6: out = s @ W_out^T (fp32 out)
  gemm_bt_a<float, EPI_PLAIN, 0><<<dim3((M / BM) * (C / BN)), blk, 0, stream>>>(
      s_bf, nullptr, Wout_bf, (float*)d_out, nullptr, nullptr, nullptr, nullptr, nullptr, M, C, C);
}